// Round 14
// baseline (5087.673 us; speedup 1.0000x reference)
//
#include <hip/hip_runtime.h>
#include <hip/hip_fp16.h>

typedef unsigned long long u64;

#define SEG_N     8192
#define NSEG      2
#define M_PER_SEG 2048
#define M_TOTAL   4096
#define CFEAT     64
#define COUT      128
#define NSAMPLE   16

#define FPS_WGS_PER_SEG 16
#define FPS_THREADS     512
#define FPS_WAVES       8
#define SLOT_STRIDE     16

// d_out layout (floats): new_xyz | new_feat | new_offset | new_vel
#define OUT_XYZ   0
#define OUT_FEAT  12288
#define OUT_OFF   536576
#define OUT_VEL   536578

// d_ws layout (bytes)
#define WS_CAND 0
#define WS_FPS  512
#define WS_KNN  16896
#define WS_SQ   (1<<19)
#define WS_D2   (1<<20)
#define D2_SEG8 ((size_t)SEG_N * SEG_N)       // 67 MB per segment (u8)

#define AG  __HIP_MEMORY_SCOPE_AGENT
#define RLX __ATOMIC_RELAXED

#define REP16(M) M(0) M(1) M(2) M(3) M(4) M(5) M(6) M(7) \
                 M(8) M(9) M(10) M(11) M(12) M(13) M(14) M(15)
#define REP16_EO(E,O) E(0) O(1) E(2) O(3) E(4) O(5) E(6) O(7) \
                      E(8) O(9) E(10) O(11) E(12) O(13) E(14) O(15)

__device__ __forceinline__ unsigned pk2(float a, float b) {
  __half2 h = __floats2half2_rn(a, b);
  unsigned u; __builtin_memcpy(&u, &h, 4); return u;
}
__device__ __forceinline__ float2 up2(unsigned u) {
  __half2 h; __builtin_memcpy(&h, &u, 4);
  return __half22float2(h);
}

template<int CTRL, int RM>
__device__ __forceinline__ unsigned dppmax(unsigned c) {
  int t = __builtin_amdgcn_update_dpp(0, (int)c, CTRL, RM, 0xF, true);
  unsigned u = (unsigned)t;
  return c > u ? c : u;
}

// ===========================================================================
// FAST PATH: u8 d^2 matrix, 67MB/segment. FPS: one WG/segment, DPP reduces,
// speculative 16-candidate row prefetch hides the HBM/L3 row-load latency.
// ===========================================================================

__global__ __launch_bounds__(256)
void norm_kernel(const float* __restrict__ xyz, const float* __restrict__ feat,
                 float* __restrict__ sq)
{
  int i = blockIdx.x * 256 + threadIdx.x;
  if (i >= NSEG * SEG_N) return;
  float a0 = xyz[(size_t)i*3+0], a1 = xyz[(size_t)i*3+1], a2 = xyz[(size_t)i*3+2];
  float acc = a0*a0 + a1*a1 + a2*a2;
  const float4* fr = (const float4*)(feat + (size_t)i * CFEAT);
  #pragma unroll
  for (int k = 0; k < 16; ++k) {
    float4 v = fr[k];
    acc += v.x*v.x + v.y*v.y + v.z*v.z + v.w*v.w;
  }
  sq[i] = acc;
}

__global__ __launch_bounds__(256)
void gram8_kernel(const float* __restrict__ xyz, const float* __restrict__ feat,
                  const float* __restrict__ sq, unsigned char* __restrict__ d2m)
{
  __shared__ float Aq[68][132];
  __shared__ float Ap[68][68];

  const int b   = blockIdx.x;
  const int s   = b >> 13;
  const int rem = b & 8191;
  const int tq  = rem >> 7;
  const int tp  = rem & 127;
  const int q0  = tq * 128, p0 = tp * 64;
  const int tid = threadIdx.x;
  unsigned char* d2seg = d2m + (size_t)s * D2_SEG8;

  for (int e = tid; e < 128 * 64; e += 256) {
    int r = e >> 6, c = e & 63;
    Aq[3 + c][r] = feat[(size_t)(s * SEG_N + q0 + r) * CFEAT + c];
  }
  for (int e = tid; e < 128 * 3; e += 256) {
    int r = e / 3, d = e - r * 3;
    Aq[d][r] = xyz[(size_t)(s * SEG_N + q0 + r) * 3 + d];
  }
  for (int e = tid; e < 64 * 64; e += 256) {
    int r = e >> 6, c = e & 63;
    Ap[3 + c][r] = feat[(size_t)(s * SEG_N + p0 + r) * CFEAT + c];
  }
  for (int e = tid; e < 64 * 3; e += 256) {
    int r = e / 3, d = e - r * 3;
    Ap[d][r] = xyz[(size_t)(s * SEG_N + p0 + r) * 3 + d];
  }
  __syncthreads();

  const int ty = tid >> 4, tx = tid & 15;
  float acc[8][4];
  #pragma unroll
  for (int i = 0; i < 8; ++i)
    #pragma unroll
    for (int j = 0; j < 4; ++j) acc[i][j] = 0.f;

  for (int k = 0; k < 67; ++k) {
    const float* aq = &Aq[k][ty * 8];
    const float* bp = &Ap[k][tx * 4];
    float a[8], bb[4];
    #pragma unroll
    for (int i = 0; i < 8; ++i) a[i] = aq[i];
    #pragma unroll
    for (int j = 0; j < 4; ++j) bb[j] = bp[j];
    #pragma unroll
    for (int i = 0; i < 8; ++i)
      #pragma unroll
      for (int j = 0; j < 4; ++j) acc[i][j] += a[i] * bb[j];
  }

  float sp[4];
  #pragma unroll
  for (int j = 0; j < 4; ++j) sp[j] = sq[s * SEG_N + p0 + tx * 4 + j];

  #pragma unroll
  for (int i = 0; i < 8; ++i) {
    int qrow = q0 + ty * 8 + i;
    float sqq = sq[s * SEG_N + qrow];
    unsigned o[4];
    #pragma unroll
    for (int j = 0; j < 4; ++j) {
      float d2 = sqq + sp[j] - 2.f * acc[i][j];
      d2 = fmaxf(d2, 0.f);
      o[j] = __float2uint_rn(fminf(d2, 255.f));
    }
    unsigned pkd = o[0] | (o[1] << 8) | (o[2] << 16) | (o[3] << 24);
    *(unsigned*)&d2seg[((size_t)qrow << 13) + (p0 + tx * 4)] = pkd;
  }
}

// warm the MALL with a read pass (reads allocate; gram's streaming writes
// apparently don't -- R13 FETCH showed ~all row loads missing L3).
__global__ __launch_bounds__(256)
void touch_kernel(const uint4* __restrict__ d2m, unsigned* __restrict__ sink)
{
  size_t i = (size_t)blockIdx.x * 256 + threadIdx.x;
  const size_t total = NSEG * D2_SEG8 / 16;
  unsigned acc = 0;
  for (size_t k = i; k < total; k += (size_t)gridDim.x * 256) {
    uint4 v = d2m[k];
    acc ^= v.x ^ v.y ^ v.z ^ v.w;
  }
  if (acc == 0x9E3779B9u) sink[0] = acc;   // practically never; defeats DCE
}

// FPS: per step ONE barrier; all 16 funnel slots vector-read; 16 speculative
// row-slice prefetches issued BEFORE the funnel reduce; winner selected from
// prefetched registers (uniform branch chain) -- no dependent row load.
__global__ __launch_bounds__(1024)
void fps_fast8_kernel(const unsigned char* __restrict__ d2m,
                      int* __restrict__ fps_idx)
{
  __shared__ unsigned wslot[2][16];

  const int tid  = threadIdx.x;
  const int lane = tid & 63;
  const int wv   = tid >> 6;
  const int s    = blockIdx.x;
  const int p0   = tid * 8;
  const unsigned idx0 = 8191 - p0;
  const unsigned char* base_s = d2m + (size_t)s * D2_SEG8;

  unsigned D0=255u,D1=255u,D2v=255u,D3=255u,D4=255u,D5=255u,D6=255u,D7=255u;

  if (tid == 0) fps_idx[s * M_PER_SEG] = 0;

  // prologue: row of q0 = 0
  uint2 cur = *(const uint2*)(base_s + p0);

  for (int t = 1; t < M_PER_SEG; ++t) {
    // min-update from cur (row of q_{t-1})
    unsigned a = cur.x, b = cur.y;
    D0 = min(D0,  a        & 255u);
    D1 = min(D1, (a >>  8) & 255u);
    D2v= min(D2v,(a >> 16) & 255u);
    D3 = min(D3,  a >> 24);
    D4 = min(D4,  b        & 255u);
    D5 = min(D5, (b >>  8) & 255u);
    D6 = min(D6, (b >> 16) & 255u);
    D7 = min(D7,  b >> 24);

    // packed candidates: dist<<13 | inv-idx (ties -> lowest point index)
    unsigned c = (D0 << 13) | idx0;
    c = max(c, (D1 << 13) | (idx0 - 1u));
    c = max(c, (D2v<< 13) | (idx0 - 2u));
    c = max(c, (D3 << 13) | (idx0 - 3u));
    c = max(c, (D4 << 13) | (idx0 - 4u));
    c = max(c, (D5 << 13) | (idx0 - 5u));
    c = max(c, (D6 << 13) | (idx0 - 6u));
    c = max(c, (D7 << 13) | (idx0 - 7u));

    // 64-lane DPP max -> lane 63
    c = dppmax<0x111, 0xF>(c);
    c = dppmax<0x112, 0xF>(c);
    c = dppmax<0x114, 0xF>(c);
    c = dppmax<0x118, 0xF>(c);
    c = dppmax<0x142, 0xA>(c);
    c = dppmax<0x143, 0xC>(c);
    unsigned wmax = (unsigned)__builtin_amdgcn_readlane((int)c, 63);

    if (lane == 0) wslot[t & 1][wv] = wmax;
    __syncthreads();                       // single barrier per step

    // vector-read all 16 slots + scalar funnel value
    const uint4* ws4 = (const uint4*)&wslot[t & 1][0];
    uint4 w0 = ws4[0], w1 = ws4[1], w2 = ws4[2], w3 = ws4[3];
    unsigned v = wslot[t & 1][lane & 15];

    // speculative prefetch: my 8B slice of each of the 16 candidate rows
#define PF(k, val) uint2 P##k = *(const uint2*)( \
      base_s + ((size_t)(8191u - ((val) & 0x1FFFu)) << 13) + p0);
    PF(0,  w0.x) PF(1,  w0.y) PF(2,  w0.z) PF(3,  w0.w)
    PF(4,  w1.x) PF(5,  w1.y) PF(6,  w1.z) PF(7,  w1.w)
    PF(8,  w2.x) PF(9,  w2.y) PF(10, w2.z) PF(11, w2.w)
    PF(12, w3.x) PF(13, w3.y) PF(14, w3.z) PF(15, w3.w)
#undef PF

    // funnel reduce over the 16 slots (overlaps the loads)
    v = dppmax<0x111, 0xF>(v);
    v = dppmax<0x112, 0xF>(v);
    v = dppmax<0x114, 0xF>(v);
    v = dppmax<0x118, 0xF>(v);
    unsigned gmax = (unsigned)__builtin_amdgcn_readlane((int)v, 15);
    int q = 8191 - (int)(gmax & 0x1FFFu);
    if (tid == 0) fps_idx[s * M_PER_SEG + t] = q;

    // select the winner's prefetched slice (winner wave = q>>9, uniform)
    int ks = q >> 9;
    cur = P0;
    if (ks ==  1) cur = P1;
    if (ks ==  2) cur = P2;
    if (ks ==  3) cur = P3;
    if (ks ==  4) cur = P4;
    if (ks ==  5) cur = P5;
    if (ks ==  6) cur = P6;
    if (ks ==  7) cur = P7;
    if (ks ==  8) cur = P8;
    if (ks ==  9) cur = P9;
    if (ks == 10) cur = P10;
    if (ks == 11) cur = P11;
    if (ks == 12) cur = P12;
    if (ks == 13) cur = P13;
    if (ks == 14) cur = P14;
    if (ks == 15) cur = P15;
  }
}

// ===========================================================================
// FALLBACK: distributed MALL-sync FPS, fp16-packed named registers.
// ===========================================================================
__global__ __attribute__((amdgpu_waves_per_eu(2, 2)))
__launch_bounds__(FPS_THREADS)
void fps_kernel(const float* __restrict__ xyz, const float* __restrict__ feat,
                u64* __restrict__ cand, int* __restrict__ fps_idx)
{
#pragma clang fp contract(off)
  __shared__ u64 wslot[FPS_WAVES];
  __shared__ int qidx_sh;

  const int tid  = threadIdx.x;
  const int lane = tid & 63;
  const int wv   = tid >> 6;
  const int s    = blockIdx.x >> 4;
  const int wg   = blockIdx.x & 15;
  const int pl   = wg * FPS_THREADS + tid;
  const size_t gr = (size_t)(s * SEG_N + pl);

  float px, py, pz;
#define DECLP(k) uint2 pp##k;
  REP16(DECLP)
  px = xyz[gr*3+0]; py = xyz[gr*3+1]; pz = xyz[gr*3+2];
  {
    const float4* fr = (const float4*)(feat + gr * CFEAT);
#define LOADP(k) { float4 v = fr[k]; pp##k.x = pk2(v.x, v.y); pp##k.y = pk2(v.z, v.w); }
    REP16(LOADP)
  }

  float qx, qy, qz;
#define DECLQ(k) float4 qf##k;
  REP16(DECLQ)
#define LOADQ1(k) qf##k = frq[k];
#define LOAD_Q(qb) { \
    qx = xyz[(qb)*3+0]; qy = xyz[(qb)*3+1]; qz = xyz[(qb)*3+2]; \
    const float4* frq = (const float4*)(feat + (qb) * CFEAT); \
    REP16(LOADQ1) }

  LOAD_Q((size_t)(s * SEG_N))
  if (tid == 0 && wg == 0) fps_idx[s * M_PER_SEG] = 0;

  float D = 1e10f;

  for (int t = 1; t < M_PER_SEG; ++t) {
    float r0=0.f, r1=0.f, r2=0.f, r3=0.f, r4=0.f, r5=0.f, r6=0.f, r7=0.f;
    {
      float tt;
      tt = px - qx; r0 += tt*tt;
      tt = py - qy; r1 += tt*tt;
      tt = pz - qz; r2 += tt*tt;
    }
#define DE(k) { float2 ab = up2(pp##k.x), cd = up2(pp##k.y); \
                float t0 = ab.x - qf##k.x; r3 += t0*t0; \
                float t1 = ab.y - qf##k.y; r4 += t1*t1; \
                float t2 = cd.x - qf##k.z; r5 += t2*t2; \
                float t3 = cd.y - qf##k.w; r6 += t3*t3; }
#define DO(k) { float2 ab = up2(pp##k.x), cd = up2(pp##k.y); \
                float t0 = ab.x - qf##k.x; r7 += t0*t0; \
                float t1 = ab.y - qf##k.y; r0 += t1*t1; \
                float t2 = cd.x - qf##k.z; r1 += t2*t2; \
                float t3 = cd.y - qf##k.w; r2 += t3*t3; }
    REP16_EO(DE, DO)
    float a = ((r0+r1)+(r2+r3)) + ((r4+r5)+(r6+r7));
    D = fminf(D, a);

    float bd = D; int bi = pl;
    #pragma unroll
    for (int off = 32; off >= 1; off >>= 1) {
      float od = __shfl_xor(bd, off);
      int   oi = __shfl_xor(bi, off);
      if (od > bd || (od == bd && oi < bi)) { bd = od; bi = oi; }
    }
    if (lane == 0)
      wslot[wv] = ((u64)__float_as_uint(bd) << 13) | (u64)(unsigned)(8191 - bi);
    __syncthreads();

    if (wv == 0) {
      u64 w = (lane < FPS_WAVES) ? wslot[lane] : 0ULL;
      #pragma unroll
      for (int off = 4; off >= 1; off >>= 1) {
        u64 o = __shfl_xor(w, off, 8);
        if (o > w) w = o;
      }
      u64* base = &cand[(((unsigned)t & 1u) * NSEG + s) * SLOT_STRIDE];
      if (lane == 0)
        __hip_atomic_store(&base[wg], ((u64)(unsigned)t << 45) | w, RLX, AG);

      u64 v = 0;
      if (lane < FPS_WGS_PER_SEG) {
        v = __hip_atomic_load(&base[lane], RLX, AG);
        while ((unsigned)(v >> 45) != (unsigned)t) {
          __builtin_amdgcn_s_sleep(1);
          v = __hip_atomic_load(&base[lane], RLX, AG);
        }
      }
      #pragma unroll
      for (int off = 8; off >= 1; off >>= 1) {
        u64 o = __shfl_xor(v, off, 16);
        if (o > v) v = o;
      }
      int qi = 8191 - (int)(v & 0x1FFFu);
      if (lane == 0) {
        qidx_sh = qi;
        if (wg == 0) fps_idx[s * M_PER_SEG + t] = qi;
      }
    }
    __syncthreads();

    LOAD_Q((size_t)(s * SEG_N + qidx_sh))
  }
}

// ---------------------------------------------------------------------------
__global__ void gather_kernel(const float* __restrict__ xyz, const float* __restrict__ vel,
                              const int* __restrict__ fps_idx, float* __restrict__ out)
{
  int i = blockIdx.x * 256 + threadIdx.x;
  if (i >= M_TOTAL) return;
  int s = i >> 11, r = i & 2047;
  int g = s * SEG_N + (fps_idx[s * M_PER_SEG + r] & 8191);
  out[OUT_XYZ + i*3 + 0] = xyz[(size_t)g*3 + 0];
  out[OUT_XYZ + i*3 + 1] = xyz[(size_t)g*3 + 1];
  out[OUT_XYZ + i*3 + 2] = xyz[(size_t)g*3 + 2];
  out[OUT_VEL + i*3 + 0] = vel[(size_t)g*3 + 0];
  out[OUT_VEL + i*3 + 1] = vel[(size_t)g*3 + 1];
  out[OUT_VEL + i*3 + 2] = vel[(size_t)g*3 + 2];
  if (i == 0) { out[OUT_OFF] = 2048.0f; out[OUT_OFF + 1] = 4096.0f; }
}

// ---------------------------------------------------------------------------
#define KNN_TILE 1024
__global__ __launch_bounds__(256)
void knn_kernel(const float* __restrict__ xyz, const float* __restrict__ out,
                int* __restrict__ knn)
{
  __shared__ float px[KNN_TILE], py[KNN_TILE], pz[KNN_TILE];
  __shared__ float ldK[16][16][16];
  __shared__ float Tq[16];
  __shared__ float dbuf[16][24];
  __shared__ int   cbuf[16][24];
  __shared__ int   cnt[16];

  const int tid = threadIdx.x;
  const int ql = tid >> 4, j = tid & 15;
  const int qg = blockIdx.x * 16 + ql;
  const int s  = qg >> 11;
  const float qx = out[OUT_XYZ + qg*3 + 0];
  const float qy = out[OUT_XYZ + qg*3 + 1];
  const float qz = out[OUT_XYZ + qg*3 + 2];
  const float sq = qx*qx + qy*qy + qz*qz;

  float K[16];
  #pragma unroll
  for (int r = 0; r < 16; ++r) K[r] = 3.4e38f;

  for (int tile = 0; tile < SEG_N / KNN_TILE; ++tile) {
    __syncthreads();
    for (int u = tid; u < KNN_TILE; u += 256) {
      size_t g = (size_t)(s * SEG_N + tile * KNN_TILE + u);
      px[u] = xyz[g*3+0]; py[u] = xyz[g*3+1]; pz[u] = xyz[g*3+2];
    }
    __syncthreads();
    #pragma unroll 4
    for (int i = 0; i < KNN_TILE / 16; ++i) {
      int c = i * 16 + j;
      float x = px[c], y = py[c], z = pz[c];
      float sp  = x*x + y*y + z*z;
      float dot = qx*x + qy*y + qz*z;
      float d2  = (sq + sp) - 2.0f * dot;
      #pragma unroll
      for (int r = 15; r >= 1; --r)
        K[r] = fminf(fmaxf(d2, K[r-1]), K[r]);
      K[0] = fminf(K[0], d2);
    }
  }
  #pragma unroll
  for (int r = 0; r < 16; ++r) ldK[ql][j][r] = K[r];
  __syncthreads();

  {
    int head = 0;
    float T = 3.4e38f;
    for (int r = 0; r < 16; ++r) {
      float val = (head < 16) ? ldK[ql][j][head] : 3.4e38f;
      float mv = val; int ml = j;
      #pragma unroll
      for (int off = 8; off >= 1; off >>= 1) {
        float ov = __shfl_xor(mv, off, 16);
        int   ol = __shfl_xor(ml, off, 16);
        if (ov < mv || (ov == mv && ol < ml)) { mv = ov; ml = ol; }
      }
      if (j == ml) head++;
      T = mv;
    }
    if (j == 0) { Tq[ql] = T; cnt[ql] = 0; }
  }
  __syncthreads();
  const float T  = Tq[ql];
  const float Tm = T + fabsf(T) * 1e-6f + 1e-30f;

  for (int tile = 0; tile < SEG_N / KNN_TILE; ++tile) {
    __syncthreads();
    for (int u = tid; u < KNN_TILE; u += 256) {
      size_t g = (size_t)(s * SEG_N + tile * KNN_TILE + u);
      px[u] = xyz[g*3+0]; py[u] = xyz[g*3+1]; pz[u] = xyz[g*3+2];
    }
    __syncthreads();
    for (int i = 0; i < KNN_TILE / 16; ++i) {
      int c = i * 16 + j;
      float x = px[c], y = py[c], z = pz[c];
      float sp  = x*x + y*y + z*z;
      float dot = qx*x + qy*y + qz*z;
      float d2  = (sq + sp) - 2.0f * dot;
      if (d2 <= Tm) {
        int pos = atomicAdd(&cnt[ql], 1);
        if (pos < 24) { dbuf[ql][pos] = d2; cbuf[ql][pos] = tile * KNN_TILE + c; }
      }
    }
  }
  __syncthreads();

  if (j == 0) {
    int n = cnt[ql]; if (n > 24) n = 24;
    for (int r = 0; r < NSAMPLE; ++r) {
      float bv = 3.4e38f; int bc = 0, bp = -1;
      for (int e = 0; e < n; ++e) {
        float dv = dbuf[ql][e]; int cc = cbuf[ql][e];
        if (dv < bv || (dv == bv && cc < bc)) { bv = dv; bc = cc; bp = e; }
      }
      if (bp >= 0) dbuf[ql][bp] = 3.4e38f;
      knn[qg * NSAMPLE + r] = bc;
    }
  }
}

// ---------------------------------------------------------------------------
__global__ __launch_bounds__(128)
void gemm_kernel(const float* __restrict__ feat, const float* __restrict__ W,
                 const int* __restrict__ knn, float* __restrict__ out)
{
  __shared__ __align__(16) float f[NSAMPLE][CFEAT];
  __shared__ int kid[NSAMPLE];
  const int tid = threadIdx.x;
  const int q = blockIdx.x;
  const int s = q >> 11;
  if (tid < NSAMPLE) kid[tid] = knn[q * NSAMPLE + tid] & 8191;
  __syncthreads();
  for (int e = tid; e < NSAMPLE * CFEAT; e += 128) {
    int k = e >> 6, c = e & 63;
    f[k][c] = feat[(size_t)(s * SEG_N + kid[k]) * CFEAT + c];
  }
  float4 w[16];
  const float4* Wrow = (const float4*)(W + (size_t)tid * CFEAT);
  #pragma unroll
  for (int c4 = 0; c4 < 16; ++c4) w[c4] = Wrow[c4];
  __syncthreads();

  float m = -3.4e38f;
  #pragma unroll
  for (int k = 0; k < NSAMPLE; ++k) {
    float acc = 0.f;
    const float4* frow = (const float4*)&f[k][0];
    #pragma unroll
    for (int c4 = 0; c4 < 16; ++c4) {
      float4 fv = frow[c4];
      acc += fv.x * w[c4].x + fv.y * w[c4].y + fv.z * w[c4].z + fv.w * w[c4].w;
    }
    m = fmaxf(m, acc);
  }
  out[OUT_FEAT + (size_t)q * COUT + tid] = fmaxf(m, 0.f);
}

// ---------------------------------------------------------------------------
extern "C" void kernel_launch(void* const* d_in, const int* in_sizes, int n_in,
                              void* d_out, int out_size, void* d_ws, size_t ws_size,
                              hipStream_t stream)
{
  const float* xyz  = (const float*)d_in[0];
  const float* feat = (const float*)d_in[1];
  // d_in[2] = offset (segment sizes fixed by the problem)
  const float* vel  = (const float*)d_in[3];
  const float* W    = (const float*)d_in[4];
  float* out = (float*)d_out;
  char*  ws  = (char*)d_ws;
  u64* cand    = (u64*)(ws + WS_CAND);
  int* fps_idx = (int*)(ws + WS_FPS);
  int* knn     = (int*)(ws + WS_KNN);

  if (ws_size >= (size_t)WS_D2 + NSEG * D2_SEG8) {
    float* sq = (float*)(ws + WS_SQ);
    unsigned char* d2m = (unsigned char*)(ws + WS_D2);
    norm_kernel<<<(NSEG * SEG_N) / 256, 256, 0, stream>>>(xyz, feat, sq);
    gram8_kernel<<<NSEG * (SEG_N / 128) * (SEG_N / 64), 256, 0, stream>>>(
        xyz, feat, sq, d2m);
    touch_kernel<<<4096, 256, 0, stream>>>((const uint4*)d2m, (unsigned*)cand);
    fps_fast8_kernel<<<NSEG, 1024, 0, stream>>>(d2m, fps_idx);
  } else {
    hipMemsetAsync(cand, 0, 512, stream);
    fps_kernel<<<NSEG * FPS_WGS_PER_SEG, FPS_THREADS, 0, stream>>>(
        xyz, feat, cand, fps_idx);
  }
  gather_kernel<<<M_TOTAL / 256, 256, 0, stream>>>(xyz, vel, fps_idx, out);
  knn_kernel<<<M_TOTAL / 16, 256, 0, stream>>>(xyz, out, knn);
  gemm_kernel<<<M_TOTAL, 128, 0, stream>>>(feat, W, knn, out);
}

// Round 15
// 2100.176 us; speedup vs baseline: 2.4225x; 2.4225x over previous
//
#include <hip/hip_runtime.h>
#include <hip/hip_fp16.h>

typedef unsigned long long u64;
typedef __attribute__((ext_vector_type(8))) short bf16x8;
typedef __attribute__((ext_vector_type(4))) float f32x4;

#define SEG_N     8192
#define NSEG      2
#define M_PER_SEG 2048
#define M_TOTAL   4096
#define CFEAT     64
#define COUT      128
#define NSAMPLE   16

#define FPS_WGS_PER_SEG 16
#define FPS_THREADS     512
#define FPS_WAVES       8
#define SLOT_STRIDE     16

// d_out layout (floats): new_xyz | new_feat | new_offset | new_vel
#define OUT_XYZ   0
#define OUT_FEAT  12288
#define OUT_OFF   536576
#define OUT_VEL   536578

// d_ws layout (bytes)
#define WS_CAND 0
#define WS_FPS  512
#define WS_KNN  16896
#define WS_SQ   (1<<19)
#define WS_D2   (1<<20)
#define D2_SEG8 ((size_t)SEG_N * SEG_N)       // 67 MB per segment (u8)

#define AG  __HIP_MEMORY_SCOPE_AGENT
#define RLX __ATOMIC_RELAXED

#define REP16(M) M(0) M(1) M(2) M(3) M(4) M(5) M(6) M(7) \
                 M(8) M(9) M(10) M(11) M(12) M(13) M(14) M(15)
#define REP16_EO(E,O) E(0) O(1) E(2) O(3) E(4) O(5) E(6) O(7) \
                      E(8) O(9) E(10) O(11) E(12) O(13) E(14) O(15)

__device__ __forceinline__ unsigned pk2(float a, float b) {
  __half2 h = __floats2half2_rn(a, b);
  unsigned u; __builtin_memcpy(&u, &h, 4); return u;
}
__device__ __forceinline__ float2 up2(unsigned u) {
  __half2 h; __builtin_memcpy(&h, &u, 4);
  return __half22float2(h);
}

template<int CTRL, int RM>
__device__ __forceinline__ unsigned dppmax(unsigned c) {
  int t = __builtin_amdgcn_update_dpp(0, (int)c, CTRL, RM, 0xF, true);
  unsigned u = (unsigned)t;
  return c > u ? c : u;
}

__device__ __forceinline__ short f2bf(float v) {
  return (short)((__float_as_uint(v) + 0x8000u) >> 16);   // RN-ish bf16
}

// ===========================================================================
// FAST PATH: u8 d^2 matrix via MFMA-bf16 gram; FPS = R13's proven kernel.
// ===========================================================================

__global__ __launch_bounds__(256)
void norm_kernel(const float* __restrict__ xyz, const float* __restrict__ feat,
                 float* __restrict__ sq)
{
  int i = blockIdx.x * 256 + threadIdx.x;
  if (i >= NSEG * SEG_N) return;
  float a0 = xyz[(size_t)i*3+0], a1 = xyz[(size_t)i*3+1], a2 = xyz[(size_t)i*3+2];
  float acc = a0*a0 + a1*a1 + a2*a2;
  const float4* fr = (const float4*)(feat + (size_t)i * CFEAT);
  #pragma unroll
  for (int k = 0; k < 16; ++k) {
    float4 v = fr[k];
    acc += v.x*v.x + v.y*v.y + v.z*v.z + v.w*v.w;
  }
  sq[i] = acc;
}

// MFMA bf16 gram: 128q x 128p u8 d^2 tile per WG. K = 96 (xyz|feat|zeros).
// Gram is symmetric and A/B share one loader formula -> k-permutation and
// row<->col transpose errors cancel; C/D mapping is the m89-verified one.
#define GKS 104   // LDS row stride in shorts (208B = 13*16, bank-spread)
__global__ __launch_bounds__(256)
void gram_mfma_kernel(const float* __restrict__ xyz, const float* __restrict__ feat,
                      const float* __restrict__ sq, unsigned char* __restrict__ d2m)
{
  __shared__ __align__(16) short Xq[128][GKS];   // 26.6 KB
  __shared__ __align__(16) short Xp[128][GKS];   // 26.6 KB  (ob overlays Xq later)
  __shared__ float sqs[128], sps[128];

  const int b   = blockIdx.x;
  const int s   = b >> 12;             // 4096 tiles per segment
  const int rem = b & 4095;
  const int tq  = rem >> 6;            // 0..63
  const int tp  = rem & 63;            // 0..63
  const int q0  = tq * 128, p0 = tp * 128;
  const int tid = threadIdx.x;
  unsigned char* d2seg = d2m + (size_t)s * D2_SEG8;

  // stage: rows 0..127 of Xq (q-points) and Xp (p-points), dims 0..95
  for (int e = tid; e < 128 * 96; e += 256) {
    int r = e / 96, c = e - r * 96;
    size_t gq = (size_t)(s * SEG_N + q0 + r);
    size_t gp = (size_t)(s * SEG_N + p0 + r);
    float vq = 0.f, vp = 0.f;
    if (c < 3)        { vq = xyz[gq*3 + c];          vp = xyz[gp*3 + c]; }
    else if (c < 67)  { vq = feat[gq*CFEAT + (c-3)]; vp = feat[gp*CFEAT + (c-3)]; }
    Xq[r][c] = f2bf(vq);
    Xp[r][c] = f2bf(vp);
  }
  if (tid < 128)      sqs[tid] = sq[s * SEG_N + q0 + tid];
  else                sps[tid - 128] = sq[s * SEG_N + p0 + (tid - 128)];
  __syncthreads();

  const int lane = tid & 63;
  const int wv   = tid >> 6;
  const int wr   = wv >> 1, wc = wv & 1;       // wave sub-block 64x64
  const int lrow = lane & 15;                  // A row / B col within frag
  const int kgr  = (lane >> 4) * 8;            // k-split within chunk

  f32x4 acc[4][4];
  #pragma unroll
  for (int i = 0; i < 4; ++i)
    #pragma unroll
    for (int j = 0; j < 4; ++j) acc[i][j] = (f32x4){0.f,0.f,0.f,0.f};

  #pragma unroll
  for (int ch = 0; ch < 3; ++ch) {
    bf16x8 af[4], bf[4];
    #pragma unroll
    for (int i = 0; i < 4; ++i)
      af[i] = *(const bf16x8*)&Xq[wr*64 + i*16 + lrow][ch*32 + kgr];
    #pragma unroll
    for (int j = 0; j < 4; ++j)
      bf[j] = *(const bf16x8*)&Xp[wc*64 + j*16 + lrow][ch*32 + kgr];
    #pragma unroll
    for (int i = 0; i < 4; ++i)
      #pragma unroll
      for (int j = 0; j < 4; ++j)
        acc[i][j] = __builtin_amdgcn_mfma_f32_16x16x32_bf16(af[i], bf[j],
                                                            acc[i][j], 0, 0, 0);
  }
  __syncthreads();   // all LDS reads done; Xq region becomes ob[128][128]

  unsigned char* ob = (unsigned char*)&Xq[0][0];
  #pragma unroll
  for (int i = 0; i < 4; ++i) {
    #pragma unroll
    for (int j = 0; j < 4; ++j) {
      #pragma unroll
      for (int reg = 0; reg < 4; ++reg) {
        int r  = wr*64 + i*16 + (lane >> 4)*4 + reg;   // C/D: m89-verified
        int cl = wc*64 + j*16 + (lane & 15);
        float d2 = sqs[r] + sps[cl] - 2.f * acc[i][j][reg];
        unsigned o;
        if (q0 + r == p0 + cl) o = 0u;
        else {
          d2 = fmaxf(d2, 0.f);
          o = __float2uint_rn(fminf(d2, 255.f));
        }
        ob[(r << 7) + cl] = (unsigned char)o;
      }
    }
  }
  __syncthreads();

  // coalesced store: 128x128 bytes = 4096 uints
  const unsigned* obu = (const unsigned*)ob;
  for (int e = tid; e < 4096; e += 256) {
    int r = e >> 5, cw = e & 31;
    *(unsigned*)&d2seg[((size_t)(q0 + r) << 13) + p0 + cw*4] = obu[e];
  }
}

// FPS from the u8 matrix (R13's proven kernel): one WG per segment (grid=2),
// 1024 threads x 8 points. Per step: one dependent 8B row-slice load, 8 u8
// mins, packed u32 candidates, DPP wave-max, parity-double-buffered 16-slot
// LDS funnel, ONE barrier, DPP funnel max + readlane -> scalar q.
__global__ __launch_bounds__(1024)
void fps_fast8_kernel(const unsigned char* __restrict__ d2m,
                      int* __restrict__ fps_idx)
{
  __shared__ unsigned wslot[2][16];

  const int tid  = threadIdx.x;
  const int lane = tid & 63;
  const int wv   = tid >> 6;
  const int s    = blockIdx.x;
  const int p0   = tid * 8;
  const unsigned idx0 = 8191 - p0;
  const unsigned char* base_s = d2m + (size_t)s * D2_SEG8;

  unsigned D0=255u,D1=255u,D2v=255u,D3=255u,D4=255u,D5=255u,D6=255u,D7=255u;

  if (tid == 0) fps_idx[s * M_PER_SEG] = 0;
  int q = 0;

  for (int t = 1; t < M_PER_SEG; ++t) {
    uint2 w = *(const uint2*)(base_s + ((size_t)q << 13) + p0);
    unsigned a = w.x, b = w.y;
    D0 = min(D0,  a        & 255u);
    D1 = min(D1, (a >>  8) & 255u);
    D2v= min(D2v,(a >> 16) & 255u);
    D3 = min(D3,  a >> 24);
    D4 = min(D4,  b        & 255u);
    D5 = min(D5, (b >>  8) & 255u);
    D6 = min(D6, (b >> 16) & 255u);
    D7 = min(D7,  b >> 24);

    unsigned c = (D0 << 13) | idx0;
    c = max(c, (D1 << 13) | (idx0 - 1u));
    c = max(c, (D2v<< 13) | (idx0 - 2u));
    c = max(c, (D3 << 13) | (idx0 - 3u));
    c = max(c, (D4 << 13) | (idx0 - 4u));
    c = max(c, (D5 << 13) | (idx0 - 5u));
    c = max(c, (D6 << 13) | (idx0 - 6u));
    c = max(c, (D7 << 13) | (idx0 - 7u));

    c = dppmax<0x111, 0xF>(c);
    c = dppmax<0x112, 0xF>(c);
    c = dppmax<0x114, 0xF>(c);
    c = dppmax<0x118, 0xF>(c);
    c = dppmax<0x142, 0xA>(c);
    c = dppmax<0x143, 0xC>(c);
    unsigned wmax = (unsigned)__builtin_amdgcn_readlane((int)c, 63);

    if (lane == 0) wslot[t & 1][wv] = wmax;
    __syncthreads();

    unsigned v = wslot[t & 1][lane & 15];
    v = dppmax<0x111, 0xF>(v);
    v = dppmax<0x112, 0xF>(v);
    v = dppmax<0x114, 0xF>(v);
    v = dppmax<0x118, 0xF>(v);
    unsigned gmax = (unsigned)__builtin_amdgcn_readlane((int)v, 15);
    q = 8191 - (int)(gmax & 0x1FFFu);
    if (tid == 0) fps_idx[s * M_PER_SEG + t] = q;
  }
}

// ===========================================================================
// FALLBACK: distributed MALL-sync FPS, fp16-packed named registers.
// ===========================================================================
__global__ __attribute__((amdgpu_waves_per_eu(2, 2)))
__launch_bounds__(FPS_THREADS)
void fps_kernel(const float* __restrict__ xyz, const float* __restrict__ feat,
                u64* __restrict__ cand, int* __restrict__ fps_idx)
{
#pragma clang fp contract(off)
  __shared__ u64 wslot[FPS_WAVES];
  __shared__ int qidx_sh;

  const int tid  = threadIdx.x;
  const int lane = tid & 63;
  const int wv   = tid >> 6;
  const int s    = blockIdx.x >> 4;
  const int wg   = blockIdx.x & 15;
  const int pl   = wg * FPS_THREADS + tid;
  const size_t gr = (size_t)(s * SEG_N + pl);

  float px, py, pz;
#define DECLP(k) uint2 pp##k;
  REP16(DECLP)
  px = xyz[gr*3+0]; py = xyz[gr*3+1]; pz = xyz[gr*3+2];
  {
    const float4* fr = (const float4*)(feat + gr * CFEAT);
#define LOADP(k) { float4 v = fr[k]; pp##k.x = pk2(v.x, v.y); pp##k.y = pk2(v.z, v.w); }
    REP16(LOADP)
  }

  float qx, qy, qz;
#define DECLQ(k) float4 qf##k;
  REP16(DECLQ)
#define LOADQ1(k) qf##k = frq[k];
#define LOAD_Q(qb) { \
    qx = xyz[(qb)*3+0]; qy = xyz[(qb)*3+1]; qz = xyz[(qb)*3+2]; \
    const float4* frq = (const float4*)(feat + (qb) * CFEAT); \
    REP16(LOADQ1) }

  LOAD_Q((size_t)(s * SEG_N))
  if (tid == 0 && wg == 0) fps_idx[s * M_PER_SEG] = 0;

  float D = 1e10f;

  for (int t = 1; t < M_PER_SEG; ++t) {
    float r0=0.f, r1=0.f, r2=0.f, r3=0.f, r4=0.f, r5=0.f, r6=0.f, r7=0.f;
    {
      float tt;
      tt = px - qx; r0 += tt*tt;
      tt = py - qy; r1 += tt*tt;
      tt = pz - qz; r2 += tt*tt;
    }
#define DE(k) { float2 ab = up2(pp##k.x), cd = up2(pp##k.y); \
                float t0 = ab.x - qf##k.x; r3 += t0*t0; \
                float t1 = ab.y - qf##k.y; r4 += t1*t1; \
                float t2 = cd.x - qf##k.z; r5 += t2*t2; \
                float t3 = cd.y - qf##k.w; r6 += t3*t3; }
#define DO(k) { float2 ab = up2(pp##k.x), cd = up2(pp##k.y); \
                float t0 = ab.x - qf##k.x; r7 += t0*t0; \
                float t1 = ab.y - qf##k.y; r0 += t1*t1; \
                float t2 = cd.x - qf##k.z; r1 += t2*t2; \
                float t3 = cd.y - qf##k.w; r2 += t3*t3; }
    REP16_EO(DE, DO)
    float a = ((r0+r1)+(r2+r3)) + ((r4+r5)+(r6+r7));
    D = fminf(D, a);

    float bd = D; int bi = pl;
    #pragma unroll
    for (int off = 32; off >= 1; off >>= 1) {
      float od = __shfl_xor(bd, off);
      int   oi = __shfl_xor(bi, off);
      if (od > bd || (od == bd && oi < bi)) { bd = od; bi = oi; }
    }
    if (lane == 0)
      wslot[wv] = ((u64)__float_as_uint(bd) << 13) | (u64)(unsigned)(8191 - bi);
    __syncthreads();

    if (wv == 0) {
      u64 w = (lane < FPS_WAVES) ? wslot[lane] : 0ULL;
      #pragma unroll
      for (int off = 4; off >= 1; off >>= 1) {
        u64 o = __shfl_xor(w, off, 8);
        if (o > w) w = o;
      }
      u64* base = &cand[(((unsigned)t & 1u) * NSEG + s) * SLOT_STRIDE];
      if (lane == 0)
        __hip_atomic_store(&base[wg], ((u64)(unsigned)t << 45) | w, RLX, AG);

      u64 v = 0;
      if (lane < FPS_WGS_PER_SEG) {
        v = __hip_atomic_load(&base[lane], RLX, AG);
        while ((unsigned)(v >> 45) != (unsigned)t) {
          __builtin_amdgcn_s_sleep(1);
          v = __hip_atomic_load(&base[lane], RLX, AG);
        }
      }
      #pragma unroll
      for (int off = 8; off >= 1; off >>= 1) {
        u64 o = __shfl_xor(v, off, 16);
        if (o > v) v = o;
      }
      int qi = 8191 - (int)(v & 0x1FFFu);
      if (lane == 0) {
        qidx_sh = qi;
        if (wg == 0) fps_idx[s * M_PER_SEG + t] = qi;
      }
    }
    __syncthreads();

    LOAD_Q((size_t)(s * SEG_N + qidx_sh))
  }
}

// ---------------------------------------------------------------------------
__global__ void gather_kernel(const float* __restrict__ xyz, const float* __restrict__ vel,
                              const int* __restrict__ fps_idx, float* __restrict__ out)
{
  int i = blockIdx.x * 256 + threadIdx.x;
  if (i >= M_TOTAL) return;
  int s = i >> 11, r = i & 2047;
  int g = s * SEG_N + (fps_idx[s * M_PER_SEG + r] & 8191);
  out[OUT_XYZ + i*3 + 0] = xyz[(size_t)g*3 + 0];
  out[OUT_XYZ + i*3 + 1] = xyz[(size_t)g*3 + 1];
  out[OUT_XYZ + i*3 + 2] = xyz[(size_t)g*3 + 2];
  out[OUT_VEL + i*3 + 0] = vel[(size_t)g*3 + 0];
  out[OUT_VEL + i*3 + 1] = vel[(size_t)g*3 + 1];
  out[OUT_VEL + i*3 + 2] = vel[(size_t)g*3 + 2];
  if (i == 0) { out[OUT_OFF] = 2048.0f; out[OUT_OFF + 1] = 4096.0f; }
}

// ---------------------------------------------------------------------------
#define KNN_TILE 1024
__global__ __launch_bounds__(256)
void knn_kernel(const float* __restrict__ xyz, const float* __restrict__ out,
                int* __restrict__ knn)
{
  __shared__ float px[KNN_TILE], py[KNN_TILE], pz[KNN_TILE];
  __shared__ float ldK[16][16][16];
  __shared__ float Tq[16];
  __shared__ float dbuf[16][24];
  __shared__ int   cbuf[16][24];
  __shared__ int   cnt[16];

  const int tid = threadIdx.x;
  const int ql = tid >> 4, j = tid & 15;
  const int qg = blockIdx.x * 16 + ql;
  const int s  = qg >> 11;
  const float qx = out[OUT_XYZ + qg*3 + 0];
  const float qy = out[OUT_XYZ + qg*3 + 1];
  const float qz = out[OUT_XYZ + qg*3 + 2];
  const float sq = qx*qx + qy*qy + qz*qz;

  float K[16];
  #pragma unroll
  for (int r = 0; r < 16; ++r) K[r] = 3.4e38f;

  for (int tile = 0; tile < SEG_N / KNN_TILE; ++tile) {
    __syncthreads();
    for (int u = tid; u < KNN_TILE; u += 256) {
      size_t g = (size_t)(s * SEG_N + tile * KNN_TILE + u);
      px[u] = xyz[g*3+0]; py[u] = xyz[g*3+1]; pz[u] = xyz[g*3+2];
    }
    __syncthreads();
    #pragma unroll 4
    for (int i = 0; i < KNN_TILE / 16; ++i) {
      int c = i * 16 + j;
      float x = px[c], y = py[c], z = pz[c];
      float sp  = x*x + y*y + z*z;
      float dot = qx*x + qy*y + qz*z;
      float d2  = (sq + sp) - 2.0f * dot;
      #pragma unroll
      for (int r = 15; r >= 1; --r)
        K[r] = fminf(fmaxf(d2, K[r-1]), K[r]);
      K[0] = fminf(K[0], d2);
    }
  }
  #pragma unroll
  for (int r = 0; r < 16; ++r) ldK[ql][j][r] = K[r];
  __syncthreads();

  {
    int head = 0;
    float T = 3.4e38f;
    for (int r = 0; r < 16; ++r) {
      float val = (head < 16) ? ldK[ql][j][head] : 3.4e38f;
      float mv = val; int ml = j;
      #pragma unroll
      for (int off = 8; off >= 1; off >>= 1) {
        float ov = __shfl_xor(mv, off, 16);
        int   ol = __shfl_xor(ml, off, 16);
        if (ov < mv || (ov == mv && ol < ml)) { mv = ov; ml = ol; }
      }
      if (j == ml) head++;
      T = mv;
    }
    if (j == 0) { Tq[ql] = T; cnt[ql] = 0; }
  }
  __syncthreads();
  const float T  = Tq[ql];
  const float Tm = T + fabsf(T) * 1e-6f + 1e-30f;

  for (int tile = 0; tile < SEG_N / KNN_TILE; ++tile) {
    __syncthreads();
    for (int u = tid; u < KNN_TILE; u += 256) {
      size_t g = (size_t)(s * SEG_N + tile * KNN_TILE + u);
      px[u] = xyz[g*3+0]; py[u] = xyz[g*3+1]; pz[u] = xyz[g*3+2];
    }
    __syncthreads();
    for (int i = 0; i < KNN_TILE / 16; ++i) {
      int c = i * 16 + j;
      float x = px[c], y = py[c], z = pz[c];
      float sp  = x*x + y*y + z*z;
      float dot = qx*x + qy*y + qz*z;
      float d2  = (sq + sp) - 2.0f * dot;
      if (d2 <= Tm) {
        int pos = atomicAdd(&cnt[ql], 1);
        if (pos < 24) { dbuf[ql][pos] = d2; cbuf[ql][pos] = tile * KNN_TILE + c; }
      }
    }
  }
  __syncthreads();

  if (j == 0) {
    int n = cnt[ql]; if (n > 24) n = 24;
    for (int r = 0; r < NSAMPLE; ++r) {
      float bv = 3.4e38f; int bc = 0, bp = -1;
      for (int e = 0; e < n; ++e) {
        float dv = dbuf[ql][e]; int cc = cbuf[ql][e];
        if (dv < bv || (dv == bv && cc < bc)) { bv = dv; bc = cc; bp = e; }
      }
      if (bp >= 0) dbuf[ql][bp] = 3.4e38f;
      knn[qg * NSAMPLE + r] = bc;
    }
  }
}

// ---------------------------------------------------------------------------
__global__ __launch_bounds__(128)
void gemm_kernel(const float* __restrict__ feat, const float* __restrict__ W,
                 const int* __restrict__ knn, float* __restrict__ out)
{
  __shared__ __align__(16) float f[NSAMPLE][CFEAT];
  __shared__ int kid[NSAMPLE];
  const int tid = threadIdx.x;
  const int q = blockIdx.x;
  const int s = q >> 11;
  if (tid < NSAMPLE) kid[tid] = knn[q * NSAMPLE + tid] & 8191;
  __syncthreads();
  for (int e = tid; e < NSAMPLE * CFEAT; e += 128) {
    int k = e >> 6, c = e & 63;
    f[k][c] = feat[(size_t)(s * SEG_N + kid[k]) * CFEAT + c];
  }
  float4 w[16];
  const float4* Wrow = (const float4*)(W + (size_t)tid * CFEAT);
  #pragma unroll
  for (int c4 = 0; c4 < 16; ++c4) w[c4] = Wrow[c4];
  __syncthreads();

  float m = -3.4e38f;
  #pragma unroll
  for (int k = 0; k < NSAMPLE; ++k) {
    float acc = 0.f;
    const float4* frow = (const float4*)&f[k][0];
    #pragma unroll
    for (int c4 = 0; c4 < 16; ++c4) {
      float4 fv = frow[c4];
      acc += fv.x * w[c4].x + fv.y * w[c4].y + fv.z * w[c4].z + fv.w * w[c4].w;
    }
    m = fmaxf(m, acc);
  }
  out[OUT_FEAT + (size_t)q * COUT + tid] = fmaxf(m, 0.f);
}

// ---------------------------------------------------------------------------
extern "C" void kernel_launch(void* const* d_in, const int* in_sizes, int n_in,
                              void* d_out, int out_size, void* d_ws, size_t ws_size,
                              hipStream_t stream)
{
  const float* xyz  = (const float*)d_in[0];
  const float* feat = (const float*)d_in[1];
  // d_in[2] = offset (segment sizes fixed by the problem)
  const float* vel  = (const float*)d_in[3];
  const float* W    = (const float*)d_in[4];
  float* out = (float*)d_out;
  char*  ws  = (char*)d_ws;
  u64* cand    = (u64*)(ws + WS_CAND);
  int* fps_idx = (int*)(ws + WS_FPS);
  int* knn     = (int*)(ws + WS_KNN);

  if (ws_size >= (size_t)WS_D2 + NSEG * D2_SEG8) {
    float* sq = (float*)(ws + WS_SQ);
    unsigned char* d2m = (unsigned char*)(ws + WS_D2);
    norm_kernel<<<(NSEG * SEG_N) / 256, 256, 0, stream>>>(xyz, feat, sq);
    gram_mfma_kernel<<<NSEG * 64 * 64, 256, 0, stream>>>(xyz, feat, sq, d2m);
    fps_fast8_kernel<<<NSEG, 1024, 0, stream>>>(d2m, fps_idx);
  } else {
    hipMemsetAsync(cand, 0, 512, stream);
    fps_kernel<<<NSEG * FPS_WGS_PER_SEG, FPS_THREADS, 0, stream>>>(
        xyz, feat, cand, fps_idx);
  }
  gather_kernel<<<M_TOTAL / 256, 256, 0, stream>>>(xyz, vel, fps_idx, out);
  knn_kernel<<<M_TOTAL / 16, 256, 0, stream>>>(xyz, out, knn);
  gemm_kernel<<<M_TOTAL, 128, 0, stream>>>(feat, W, knn, out);
}